// Round 17
// baseline (260.870 us; speedup 1.0000x reference)
//
#include <hip/hip_runtime.h>

#define NNODES 4096
#define NCH    128
#define NE     10
#define PADN   4736          // 74 chunks * 64 (worst-case 64-padded buckets)
#define NCHUNK 74
#define TSTRIDE 2048         // per-(e,c) table stride (floats)
#define DGSTRIDE 672         // per-dgroup interleaved stream stride (219*3=657, padded to x16)

// ---------------- workspace layout (floats) ----------------
// int   chunkinfo[96]            @0      ([0..80): beg|valid<<16|e<<24, -1=unused;
//                                         [80..91): cbase[e] chunk-range bases)
// int   list[PADN]               @96     (-1 = padding slot)
// float pre  [NCH][9][PADN]      @4864        (5,455,872)
// float mixed[NCH][9][PADN]      @5,460,736   (5,455,872)
// float wcat [3][NE][128][48]    @10,916,608  (184,320)   (c-major, k fastest)
// float Usym [9][219][48]        @11,100,928  (94,608)
// total ~45 MB.  NOTE: Sws eliminated — each k_main block builds its own
// table from Usym (L2-resident) + its wcat row.

// ---------------- symmetric-stream decode table ----------------
struct MTab { unsigned short v[220]; };
static constexpr MTab make_mtab() {
    MTab t{};
    int m = 0;
    for (int i = 0; i < 9; ++i) {
        t.v[m++] = (unsigned short)((1 << 12) | (i << 8) | (i << 4) | i);
        for (int j = i; j < 9; ++j) {
            t.v[m++] = (unsigned short)((2 << 12) | (i << 8) | (j << 4) | j);
            for (int n = j; n < 9; ++n)
                t.v[m++] = (unsigned short)((3 << 12) | (i << 8) | (j << 4) | n);
        }
    }
    return t;   // m == 219
}
__constant__ MTab c_mtab = make_mtab();

// ---------------- prep: bucketing (blk 0) + wcat (blk 1..10) + Usym (blk 11..19) ----------------
__global__ __launch_bounds__(1024) void k_prep(
    const float* __restrict__ attrs,
    const float* __restrict__ U3_0, const float* __restrict__ U3_1, const float* __restrict__ U3_2,
    const float* __restrict__ W3_0, const float* __restrict__ W3_1, const float* __restrict__ W3_2,
    const float* __restrict__ U2_0, const float* __restrict__ U2_1, const float* __restrict__ U2_2,
    const float* __restrict__ W2_0, const float* __restrict__ W2_1, const float* __restrict__ W2_2,
    const float* __restrict__ U1_0, const float* __restrict__ U1_1, const float* __restrict__ U1_2,
    const float* __restrict__ W1_0, const float* __restrict__ W1_1, const float* __restrict__ W1_2,
    int* __restrict__ list, int* __restrict__ chunkinfo,
    float* __restrict__ wcat, float* __restrict__ Usym)
{
    int bid = blockIdx.x, t = threadIdx.x;
    if (bid == 0) {
        // ---- bucketing via ballot counts + shfl prefix-scan (zero atomics) ----
        __shared__ int cnt[64][NE];    // [wi = w*4+k][e]
        __shared__ int pfx[64][NE];    // exclusive prefix within e over wi
        __shared__ int tot[NE];
        __shared__ int base[NE + 1], cbase[NE + 1];
        int w = t >> 6, lane = t & 63;
        unsigned long long lmask = (1ull << lane) - 1ull;
        int mye[4];
#pragma unroll
        for (int k = 0; k < 4; ++k) {
            int b = k * 1024 + t;
            const float* y = attrs + (size_t)b * NE;
            int e = 0;
#pragma unroll
            for (int u = 0; u < NE; ++u) if (y[u] > 0.5f) e = u;
            mye[k] = e;
#pragma unroll
            for (int u = 0; u < NE; ++u) {
                unsigned long long mb = __ballot(e == u);
                if (lane == 0) cnt[w * 4 + k][u] = __popcll(mb);
            }
        }
        for (int i = t; i < PADN; i += 1024) list[i] = -1;
        __syncthreads();
        if (t < 640) {                 // wave e scans its 64 (wi) entries
            int e = t >> 6, wi = t & 63;
            int v = cnt[wi][e];
            int inc = v;
#pragma unroll
            for (int d = 1; d < 64; d <<= 1) {
                int o = __shfl_up(inc, d, 64);
                if (wi >= d) inc += o;
            }
            pfx[wi][e] = inc - v;
            if (wi == 63) tot[e] = inc;
        }
        __syncthreads();
        if (t == 0) {
            int off = 0, goff = 0;
            for (int e = 0; e < NE; ++e) {
                base[e] = off; cbase[e] = goff;
                int nc = (tot[e] + 63) >> 6;
                off += nc * 64; goff += nc;
            }
            base[NE] = off; cbase[NE] = goff;
        }
        __syncthreads();
        if (t < 80) {
            int info = -1;
            if (t < cbase[NE]) {
                int e = 0;
                while (!(t >= cbase[e] && t < cbase[e + 1])) ++e;
                int k = t - cbase[e];
                int valid = tot[e] - k * 64; if (valid > 64) valid = 64;
                info = (base[e] + k * 64) | (valid << 16) | (e << 24);
            }
            chunkinfo[t] = info;
        } else if (t < 91) {
            chunkinfo[t] = cbase[t - 80];          // per-element chunk ranges
        }
#pragma unroll
        for (int k = 0; k < 4; ++k) {
            int e = mye[k];
#pragma unroll
            for (int u = 0; u < NE; ++u) {
                unsigned long long mb = __ballot(e == u);
                if (e == u) {
                    int pos = base[u] + pfx[w * 4 + k][u] + __popcll(mb & lmask);
                    list[pos] = k * 1024 + t;
                }
            }
        }
    } else if (bid <= 10) {
        // ---- wcat build: one e, layout [L][e][c][48] (c-major, k fastest) ----
        int e = bid - 1;
#pragma unroll 1
        for (int L = 0; L < 3; ++L) {
            const float* W1 = (L == 0) ? W1_0 : (L == 1) ? W1_1 : W1_2;
            const float* W2 = (L == 0) ? W2_0 : (L == 1) ? W2_1 : W2_2;
            const float* W3 = (L == 0) ? W3_0 : (L == 1) ? W3_1 : W3_2;
            for (int it = t; it < 128 * 48; it += 1024) {
                int c = it / 48, k = it - c * 48;
                float v = 0.0f;
                if (k < 4)       v = W1[((size_t)e * 4 + k) * 128 + c];
                else if (k < 16) v = W2[((size_t)e * 12 + (k - 4)) * 128 + c];
                else if (k < 46) v = W3[((size_t)e * 30 + (k - 16)) * 128 + c];
                wcat[(((size_t)L * NE + e) * 128) * 48 + it] = v;
            }
        }
    } else {
        // ---- Usym build: one D, 219 m x 48 k, orbit-summed (built ONCE, L2-served) ----
        int D = bid - 11;
        const float *U3, *U2, *U1; int dloc;
        if (D == 0)      { U3 = U3_0; U2 = U2_0; U1 = U1_0; dloc = 0; }
        else if (D < 4)  { U3 = U3_1; U2 = U2_1; U1 = U1_1; dloc = D - 1; }
        else             { U3 = U3_2; U2 = U2_2; U1 = U1_2; dloc = D - 4; }
        for (int it = t; it < 219 * 48; it += 1024) {
            int m = it / 48, k = it - m * 48;
            unsigned mv = c_mtab.v[m];
            int kind = mv >> 12, i = (mv >> 8) & 15, j = (mv >> 4) & 15, n = mv & 15;
            float v = 0.0f;
            if (kind == 1) {
                if (k < 4) v = U1[(size_t)(dloc * 9 + i) * 4 + k];
            } else if (kind == 2) {
                if (k >= 4 && k < 16) {
                    int kk = k - 4;
                    v = U2[(size_t)(dloc * 81 + i * 9 + j) * 12 + kk];
                    if (i != j) v += U2[(size_t)(dloc * 81 + j * 9 + i) * 12 + kk];
                }
            } else {
                if (k >= 16 && k < 46) {
                    int kk = k - 16;
                    v = U3[((size_t)dloc * 729 + i * 81 + j * 9 + n) * 30 + kk];
                    if (i == j) {
                        if (j != n)
                            v += U3[((size_t)dloc * 729 + i * 81 + n * 9 + i) * 30 + kk]
                               + U3[((size_t)dloc * 729 + n * 81 + i * 9 + i) * 30 + kk];
                    } else if (j == n) {
                        v += U3[((size_t)dloc * 729 + j * 81 + i * 9 + j) * 30 + kk]
                           + U3[((size_t)dloc * 729 + j * 81 + j * 9 + i) * 30 + kk];
                    } else {
                        v += U3[((size_t)dloc * 729 + i * 81 + n * 9 + j) * 30 + kk]
                           + U3[((size_t)dloc * 729 + j * 81 + i * 9 + n) * 30 + kk]
                           + U3[((size_t)dloc * 729 + j * 81 + n * 9 + i) * 30 + kk]
                           + U3[((size_t)dloc * 729 + n * 81 + i * 9 + j) * 30 + kk]
                           + U3[((size_t)dloc * 729 + n * 81 + j * 9 + i) * 30 + kk];
                    }
                }
            }
            Usym[((size_t)D * 219 + m) * 48 + k] = v;
        }
    }
}

// ---------------- main contraction helper: NB chunks per wave (round-10 proven form) ----------------
template <int NB>
__device__ __forceinline__ void do_chunks(
    const float* __restrict__ tab, const float* __restrict__ nf,
    const int* __restrict__ list, const int* __restrict__ chunkinfo,
    float* __restrict__ prep, int c, int gi, int lane)
{
    int pos[NB];
    float x[NB][9];
#pragma unroll
    for (int u = 0; u < NB; ++u) {
        int info = __builtin_amdgcn_readfirstlane(chunkinfo[gi + u]);
        pos[u] = (info & 0xffff) + lane;
        int b = list[pos[u]];
        const float* xp = nf + ((size_t)(b < 0 ? 0 : b) * 128 + c) * 9;
#pragma unroll
        for (int n = 0; n < 9; ++n) x[u][n] = (b >= 0) ? xp[n] : 0.0f;
    }

#pragma unroll 1
    for (int dg = 0; dg < 3; ++dg) {
        const float* s = tab + dg * DGSTRIDE;   // LDS, wave-uniform addrs
        float a3[NB][3];
#pragma unroll
        for (int u = 0; u < NB; ++u)
#pragma unroll
            for (int d = 0; d < 3; ++d) a3[u][d] = 0.0f;
        int p = 0;
#pragma unroll
        for (int i = 0; i < 9; ++i) {
            float a2[NB][3];
#pragma unroll
            for (int d = 0; d < 3; ++d) {
                float tv = s[p + d];
#pragma unroll
                for (int u = 0; u < NB; ++u) a2[u][d] = tv;
            }
            p += 3;
#pragma unroll
            for (int j = i; j < 9; ++j) {
                float a1[NB][3];
#pragma unroll
                for (int d = 0; d < 3; ++d) {
                    float tv = s[p + d];
#pragma unroll
                    for (int u = 0; u < NB; ++u) a1[u][d] = tv;
                }
                p += 3;
#pragma unroll
                for (int n = j; n < 9; ++n) {
#pragma unroll
                    for (int d = 0; d < 3; ++d) {
                        float tv = s[p + d];
#pragma unroll
                        for (int u = 0; u < NB; ++u)
                            a1[u][d] = fmaf(tv, x[u][n], a1[u][d]);
                    }
                    p += 3;
                }
#pragma unroll
                for (int u = 0; u < NB; ++u)
#pragma unroll
                    for (int d = 0; d < 3; ++d)
                        a2[u][d] = fmaf(a1[u][d], x[u][j], a2[u][d]);
            }
#pragma unroll
            for (int u = 0; u < NB; ++u)
#pragma unroll
                for (int d = 0; d < 3; ++d)
                    a3[u][d] = fmaf(a2[u][d], x[u][i], a3[u][d]);
        }
#pragma unroll
        for (int u = 0; u < NB; ++u)
#pragma unroll
            for (int d = 0; d < 3; ++d)
                prep[(size_t)(dg * 3 + d) * PADN + pos[u]] = a3[u][d];
    }
}

// ---------------- main contraction: block = (c, e), table built IN-BLOCK ----------------
// Prologue: 1971 table entries = dots of Usym rows (contiguous 192B, L2-resident)
// with this block's wcat row (block-uniform base) -> LDS tab. Replaces the
// separate k_tab kernel + Sws HBM round-trip. Then the proven R10 chunk loop.
__global__ __launch_bounds__(256) void k_main(
    const float* __restrict__ nf, const int* __restrict__ list,
    const int* __restrict__ chunkinfo, const float* __restrict__ wcat,
    const float* __restrict__ Usym, float* __restrict__ pre)
{
    __shared__ __align__(16) float tab[TSTRIDE];   // 8 KB, shared by all 4 waves
    int c = blockIdx.x, e = blockIdx.y;
    int t = threadIdx.x;
    int w = t >> 6, lane = t & 63;
    int cb0 = chunkinfo[80 + e], cb1 = chunkinfo[81 + e];
    if (cb0 >= cb1) return;

    // ---- build this (e,c)'s table: 1971 entries, ~8 dots/thread ----
#pragma unroll 1
    for (int idx = t; idx < 1971; idx += 256) {
        int dg = idx / 657, r = idx - dg * 657;
        int m = r / 3, dr = r - m * 3;
        int D = dg * 3 + dr;
        int L = (D == 0) ? 0 : (D < 4 ? 1 : 2);
        const float* wc = wcat + (((size_t)L * NE + e) * 128 + c) * 48;
        const float* up = Usym + ((size_t)D * 219 + m) * 48;
        unsigned mv = c_mtab.v[m];
        int kind = mv >> 12;
        float a = 0.0f;
        if (kind == 1) {
#pragma unroll
            for (int k = 0; k < 4; ++k) a = fmaf(up[k], wc[k], a);
        } else if (kind == 2) {
#pragma unroll
            for (int k = 4; k < 16; ++k) a = fmaf(up[k], wc[k], a);
        } else {
#pragma unroll
            for (int k = 16; k < 46; ++k) a = fmaf(up[k], wc[k], a);
        }
        tab[dg * DGSTRIDE + m * 3 + dr] = a;
    }
    __syncthreads();

    float* prep = pre + (size_t)c * 9 * PADN;

#pragma unroll 1
    for (int gi = cb0 + 2 * w; gi < cb1; gi += 8) {
        if (gi + 1 < cb1)
            do_chunks<2>(tab, nf, list, chunkinfo, prep, c, gi, lane);
        else
            do_chunks<1>(tab, nf, list, chunkinfo, prep, c, gi, lane);
    }
}

// ---------------- channel-mix GEMM (R11 form: two f-half blocks per n-tile) ----------------
__global__ __launch_bounds__(256) void k_mix(
    const float* __restrict__ pre, const int* __restrict__ chunkinfo,
    const float* __restrict__ lin0, const float* __restrict__ lin1,
    const float* __restrict__ lin2, float* __restrict__ mixed)
{
    __shared__ __align__(16) float pt[128 * 64];   // 32 KB
    int bid = blockIdx.x;
    int nt = bid >> 1;                 // n-tile 0..665
    int fbase = (bid & 1) * 64;        // adjacent blocks share the n-tile (L2 reuse)
    int n0 = nt * 64;
    int D = nt / NCHUNK;
    int g = nt - D * NCHUNK;
    if (chunkinfo[g] == -1) return;
    const float* lin = (D == 0) ? lin0 : (D < 4 ? lin1 : lin2);
    int t = threadIdx.x;

    {
        int q4 = (t & 15) * 4;
        int cb = t >> 4;
#pragma unroll
        for (int k = 0; k < 8; ++k) {
            int c = cb + k * 16;
            float4 v = *(const float4*)&pre[(size_t)c * 9 * PADN + n0 + q4];
            *(float4*)&pt[c * 64 + q4] = v;
        }
    }
    __syncthreads();

    int tq = t & 63;
    int f0 = fbase + __builtin_amdgcn_readfirstlane(t >> 6) * 16;
    float acc[16];
#pragma unroll
    for (int f = 0; f < 16; ++f) acc[f] = 0.0f;

#pragma unroll 4
    for (int c = 0; c < 128; ++c) {
        float pv = pt[c * 64 + tq];
        const float* lr = lin + c * 128 + f0;
#pragma unroll
        for (int f = 0; f < 16; ++f)
            acc[f] = fmaf(pv, lr[f], acc[f]);
    }

    const float nrm = 0.08838834764831845f;   // 1/sqrt(128)
#pragma unroll
    for (int f = 0; f < 16; ++f)
        mixed[(size_t)(f0 + f) * 9 * PADN + n0 + tq] = acc[f] * nrm;
}

// ---------------- output permute + sc add ----------------
__global__ __launch_bounds__(256) void k_out(
    const float* __restrict__ mixed, const int* __restrict__ list,
    const int* __restrict__ chunkinfo, const float* __restrict__ sc,
    float* __restrict__ out)
{
    __shared__ float tr[64 * 73];      // [q][row], row = f*9+D, pad 73
    int fc = blockIdx.x, g = blockIdx.y;
    if (chunkinfo[g] == -1) return;
    int t = threadIdx.x;
    int fbase = fc * 8;
    int tf = t >> 6, tq = t & 63;

    // phase 1: load 72 rows x 64 q, coalesced along q
#pragma unroll
    for (int k = 0; k < 18; ++k) {
        int row = k * 4 + tf;                      // 0..71
        int f = row / 9, D = row - f * 9;
        float v = mixed[((size_t)(fbase + f) * 9 + D) * PADN + g * 64 + tq];
        tr[tq * 73 + row] = v;
    }
    __syncthreads();

    // phase 2: 64 nodes * 72 out-cols, contiguous segments per node
#pragma unroll 1
    for (int k = 0; k < 18; ++k) {
        int idx = k * 256 + t;
        int node = idx / 72, col = idx - node * 72;
        int b = list[g * 64 + node];
        if (b < 0) continue;
        int row, gcol;
        if (col < 8)       { row = col * 9;                       gcol = fbase + col; }
        else if (col < 32) { int u = col - 8;  int f = u / 3, dl = u - f * 3;
                             row = f * 9 + 1 + dl;                gcol = 128 + fbase * 3 + u; }
        else               { int u = col - 32; int f = u / 5, dl = u - f * 5;
                             row = f * 9 + 4 + dl;                gcol = 512 + fbase * 5 + u; }
        out[(size_t)b * 1152 + gcol] = tr[node * 73 + row] + sc[(size_t)b * 1152 + gcol];
    }
}

// ---------------- launch ----------------
extern "C" void kernel_launch(void* const* d_in, const int* in_sizes, int n_in,
                              void* d_out, int out_size, void* d_ws, size_t ws_size,
                              hipStream_t stream)
{
    const float* nf    = (const float*)d_in[0];
    const float* sc    = (const float*)d_in[1];
    const float* attrs = (const float*)d_in[2];
    const float *U3s[3], *U2s[3], *U1s[3], *W3s[3], *W2s[3], *W1s[3], *lins[3];
    for (int L = 0; L < 3; ++L) {
        const int o = 3 + 7 * L;
        U3s[L]  = (const float*)d_in[o + 0];
        U2s[L]  = (const float*)d_in[o + 1];
        U1s[L]  = (const float*)d_in[o + 2];
        W3s[L]  = (const float*)d_in[o + 3];
        W2s[L]  = (const float*)d_in[o + 4];
        W1s[L]  = (const float*)d_in[o + 5];
        lins[L] = (const float*)d_in[o + 6];
    }

    float* wsf     = (float*)d_ws;
    int* chunkinfo = (int*)d_ws;
    int* list      = chunkinfo + 96;
    float* pre   = wsf + 4864;                           // 5,455,872
    float* mixed = pre + (size_t)NCH * 9 * PADN;         // 5,455,872
    float* wcat  = mixed + (size_t)NCH * 9 * PADN;       // 184,320
    float* Usym  = wcat + (size_t)3 * NE * 128 * 48;     // 94,608

    k_prep<<<20, 1024, 0, stream>>>(attrs,
                                    U3s[0], U3s[1], U3s[2], W3s[0], W3s[1], W3s[2],
                                    U2s[0], U2s[1], U2s[2], W2s[0], W2s[1], W2s[2],
                                    U1s[0], U1s[1], U1s[2], W1s[0], W1s[1], W1s[2],
                                    list, chunkinfo, wcat, Usym);
    k_main<<<dim3(128, 10), 256, 0, stream>>>(nf, list, chunkinfo, wcat, Usym, pre);
    k_mix<<<1332, 256, 0, stream>>>(pre, chunkinfo, lins[0], lins[1], lins[2], mixed);
    k_out<<<dim3(16, NCHUNK), 256, 0, stream>>>(mixed, list, chunkinfo, sc, (float*)d_out);
}

// Round 18
// 236.484 us; speedup vs baseline: 1.1031x; 1.1031x over previous
//
#include <hip/hip_runtime.h>

#define NNODES 4096
#define NCH    128
#define NE     10
#define PADN   4736          // 74 chunks * 64 (worst-case 64-padded buckets)
#define NCHUNK 74
#define TSTRIDE 2048         // per-(e,c) table stride (floats)
#define DGSTRIDE 672         // per-dgroup interleaved stream stride (219*3=657, padded to x16)

// ---------------- workspace layout (floats) ----------------
// int   chunkinfo[96]            @0      ([0..80): beg|valid<<16|e<<24, -1=unused;
//                                         [80..91): cbase[e] chunk-range bases)
// int   list[PADN]               @96     (-1 = padding slot)
// float Sws [NE][NCH][TSTRIDE]   @4864        (2,621,440)
// float pre [NCH][9][PADN]       @2,626,304   (5,455,872)
// float mixed[NCH][9][PADN]      @8,082,176   (5,455,872)
// float wcat[3][NE][48][128]     @13,538,048  (184,320)   (k-major, c fastest)
// float Usym[9][219][48]         @13,722,368  (94,608)
// total ~55 MB

// ---------------- symmetric-stream decode table ----------------
struct MTab { unsigned short v[220]; };
static constexpr MTab make_mtab() {
    MTab t{};
    int m = 0;
    for (int i = 0; i < 9; ++i) {
        t.v[m++] = (unsigned short)((1 << 12) | (i << 8) | (i << 4) | i);
        for (int j = i; j < 9; ++j) {
            t.v[m++] = (unsigned short)((2 << 12) | (i << 8) | (j << 4) | j);
            for (int n = j; n < 9; ++n)
                t.v[m++] = (unsigned short)((3 << 12) | (i << 8) | (j << 4) | n);
        }
    }
    return t;   // m == 219
}
__constant__ MTab c_mtab = make_mtab();

// ---------------- prep: bucketing (blk 0) + wcat (blk 1..10) + Usym (blk 11..19) ----------------
__global__ __launch_bounds__(1024) void k_prep(
    const float* __restrict__ attrs,
    const float* __restrict__ U3_0, const float* __restrict__ U3_1, const float* __restrict__ U3_2,
    const float* __restrict__ W3_0, const float* __restrict__ W3_1, const float* __restrict__ W3_2,
    const float* __restrict__ U2_0, const float* __restrict__ U2_1, const float* __restrict__ U2_2,
    const float* __restrict__ W2_0, const float* __restrict__ W2_1, const float* __restrict__ W2_2,
    const float* __restrict__ U1_0, const float* __restrict__ U1_1, const float* __restrict__ U1_2,
    const float* __restrict__ W1_0, const float* __restrict__ W1_1, const float* __restrict__ W1_2,
    int* __restrict__ list, int* __restrict__ chunkinfo,
    float* __restrict__ wcat, float* __restrict__ Usym)
{
    int bid = blockIdx.x, t = threadIdx.x;
    if (bid == 0) {
        // ---- bucketing via ballot counts + shfl prefix-scan (zero atomics) ----
        __shared__ int cnt[64][NE];    // [wi = w*4+k][e]
        __shared__ int pfx[64][NE];    // exclusive prefix within e over wi
        __shared__ int tot[NE];
        __shared__ int base[NE + 1], cbase[NE + 1];
        int w = t >> 6, lane = t & 63;
        unsigned long long lmask = (1ull << lane) - 1ull;
        int mye[4];
#pragma unroll
        for (int k = 0; k < 4; ++k) {
            int b = k * 1024 + t;
            const float* y = attrs + (size_t)b * NE;
            int e = 0;
#pragma unroll
            for (int u = 0; u < NE; ++u) if (y[u] > 0.5f) e = u;
            mye[k] = e;
#pragma unroll
            for (int u = 0; u < NE; ++u) {
                unsigned long long mb = __ballot(e == u);
                if (lane == 0) cnt[w * 4 + k][u] = __popcll(mb);
            }
        }
        for (int i = t; i < PADN; i += 1024) list[i] = -1;
        __syncthreads();
        if (t < 640) {                 // wave e scans its 64 (wi) entries
            int e = t >> 6, wi = t & 63;
            int v = cnt[wi][e];
            int inc = v;
#pragma unroll
            for (int d = 1; d < 64; d <<= 1) {
                int o = __shfl_up(inc, d, 64);
                if (wi >= d) inc += o;
            }
            pfx[wi][e] = inc - v;
            if (wi == 63) tot[e] = inc;
        }
        __syncthreads();
        if (t == 0) {
            int off = 0, goff = 0;
            for (int e = 0; e < NE; ++e) {
                base[e] = off; cbase[e] = goff;
                int nc = (tot[e] + 63) >> 6;
                off += nc * 64; goff += nc;
            }
            base[NE] = off; cbase[NE] = goff;
        }
        __syncthreads();
        if (t < 80) {
            int info = -1;
            if (t < cbase[NE]) {
                int e = 0;
                while (!(t >= cbase[e] && t < cbase[e + 1])) ++e;
                int k = t - cbase[e];
                int valid = tot[e] - k * 64; if (valid > 64) valid = 64;
                info = (base[e] + k * 64) | (valid << 16) | (e << 24);
            }
            chunkinfo[t] = info;
        } else if (t < 91) {
            chunkinfo[t] = cbase[t - 80];          // per-element chunk ranges
        }
#pragma unroll
        for (int k = 0; k < 4; ++k) {
            int e = mye[k];
#pragma unroll
            for (int u = 0; u < NE; ++u) {
                unsigned long long mb = __ballot(e == u);
                if (e == u) {
                    int pos = base[u] + pfx[w * 4 + k][u] + __popcll(mb & lmask);
                    list[pos] = k * 1024 + t;
                }
            }
        }
    } else if (bid <= 10) {
        // ---- wcat build: one e, 3 L x 48 k x 128 c, c fastest (coalesced) ----
        int e = bid - 1;
#pragma unroll 1
        for (int L = 0; L < 3; ++L) {
            const float* W1 = (L == 0) ? W1_0 : (L == 1) ? W1_1 : W1_2;
            const float* W2 = (L == 0) ? W2_0 : (L == 1) ? W2_1 : W2_2;
            const float* W3 = (L == 0) ? W3_0 : (L == 1) ? W3_1 : W3_2;
            for (int it = t; it < 48 * 128; it += 1024) {
                int c = it & 127, k = it >> 7;
                float v = 0.0f;
                if (k < 4)       v = W1[((size_t)e * 4 + k) * 128 + c];
                else if (k < 16) v = W2[((size_t)e * 12 + (k - 4)) * 128 + c];
                else if (k < 46) v = W3[((size_t)e * 30 + (k - 16)) * 128 + c];
                wcat[(((size_t)L * NE + e) * 48 + k) * 128 + c] = v;
            }
        }
    } else {
        // ---- Usym build: one D, 219 m x 48 k, orbit-summed (built ONCE, L2-served) ----
        int D = bid - 11;
        const float *U3, *U2, *U1; int dloc;
        if (D == 0)      { U3 = U3_0; U2 = U2_0; U1 = U1_0; dloc = 0; }
        else if (D < 4)  { U3 = U3_1; U2 = U2_1; U1 = U1_1; dloc = D - 1; }
        else             { U3 = U3_2; U2 = U2_2; U1 = U1_2; dloc = D - 4; }
        for (int it = t; it < 219 * 48; it += 1024) {
            int m = it / 48, k = it - m * 48;
            unsigned mv = c_mtab.v[m];
            int kind = mv >> 12, i = (mv >> 8) & 15, j = (mv >> 4) & 15, n = mv & 15;
            float v = 0.0f;
            if (kind == 1) {
                if (k < 4) v = U1[(size_t)(dloc * 9 + i) * 4 + k];
            } else if (kind == 2) {
                if (k >= 4 && k < 16) {
                    int kk = k - 4;
                    v = U2[(size_t)(dloc * 81 + i * 9 + j) * 12 + kk];
                    if (i != j) v += U2[(size_t)(dloc * 81 + j * 9 + i) * 12 + kk];
                }
            } else {
                if (k >= 16 && k < 46) {
                    int kk = k - 16;
                    v = U3[((size_t)dloc * 729 + i * 81 + j * 9 + n) * 30 + kk];
                    if (i == j) {
                        if (j != n)
                            v += U3[((size_t)dloc * 729 + i * 81 + n * 9 + i) * 30 + kk]
                               + U3[((size_t)dloc * 729 + n * 81 + i * 9 + i) * 30 + kk];
                    } else if (j == n) {
                        v += U3[((size_t)dloc * 729 + j * 81 + i * 9 + j) * 30 + kk]
                           + U3[((size_t)dloc * 729 + j * 81 + j * 9 + i) * 30 + kk];
                    } else {
                        v += U3[((size_t)dloc * 729 + i * 81 + n * 9 + j) * 30 + kk]
                           + U3[((size_t)dloc * 729 + j * 81 + i * 9 + n) * 30 + kk]
                           + U3[((size_t)dloc * 729 + j * 81 + n * 9 + i) * 30 + kk]
                           + U3[((size_t)dloc * 729 + n * 81 + i * 9 + j) * 30 + kk]
                           + U3[((size_t)dloc * 729 + n * 81 + j * 9 + i) * 30 + kk];
                    }
                }
            }
            Usym[((size_t)D * 219 + m) * 48 + k] = v;
        }
    }
}

// ---------------- table GEMM with coalesced writes ----------------
// block = (e, dg, mh): 28 m x 3 dr x 128 c. Compute lane=c into LDS tile
// [row][129], then transposed write phase: wave owns 32 c's, lane=row ->
// consecutive addresses (256B coalesced stores).
__global__ __launch_bounds__(256) void k_tab(
    const float* __restrict__ wcat, const float* __restrict__ Usym,
    float* __restrict__ Sws)
{
    __shared__ __align__(16) float tile[84 * 129];   // 43.3 KB
    int bid = blockIdx.x;
    int e = bid / 24, r0 = bid - e * 24;
    int dg = r0 >> 3, mh = r0 & 7;
    int m0 = mh * 28, m1 = m0 + 28; if (m1 > 219) m1 = 219;
    int t = threadIdx.x;
    int c = t & 127;
    int sub = __builtin_amdgcn_readfirstlane(t >> 7);   // 0..1, wave-uniform
    int D0 = dg * 3;
    int LA = (D0 == 0) ? 0 : (D0 < 4 ? 1 : 2);
    int LB = (D0 + 1 < 4) ? 1 : 2;

    float wcA[48], wcB[48];
#pragma unroll
    for (int k = 0; k < 48; ++k) {
        wcA[k] = wcat[(((size_t)LA * NE + e) * 48 + k) * 128 + c];
        wcB[k] = wcat[(((size_t)LB * NE + e) * 48 + k) * 128 + c];
    }

#pragma unroll 1
    for (int m = m0 + sub; m < m1; m += 2) {
        unsigned mv = c_mtab.v[m];
        int kind = mv >> 12;
        const float* up0 = Usym + ((size_t)D0 * 219 + m) * 48;
        const float* up1 = up0 + 219 * 48;
        const float* up2 = up1 + 219 * 48;
        float a0 = 0.0f, a1 = 0.0f, a2 = 0.0f;
        if (kind == 1) {
#pragma unroll
            for (int k = 0; k < 4; ++k) {
                a0 = fmaf(up0[k], wcA[k], a0);
                a1 = fmaf(up1[k], wcB[k], a1);
                a2 = fmaf(up2[k], wcB[k], a2);
            }
        } else if (kind == 2) {
#pragma unroll
            for (int k = 4; k < 16; ++k) {
                a0 = fmaf(up0[k], wcA[k], a0);
                a1 = fmaf(up1[k], wcB[k], a1);
                a2 = fmaf(up2[k], wcB[k], a2);
            }
        } else {
#pragma unroll
            for (int k = 16; k < 46; ++k) {
                a0 = fmaf(up0[k], wcA[k], a0);
                a1 = fmaf(up1[k], wcB[k], a1);
                a2 = fmaf(up2[k], wcB[k], a2);
            }
        }
        int rr = (m - m0) * 3;
        tile[(rr + 0) * 129 + c] = a0;
        tile[(rr + 1) * 129 + c] = a1;
        tile[(rr + 2) * 129 + c] = a2;
    }
    __syncthreads();

    // transposed write: wave w owns c in [w*32, w*32+32); lane = row
    int w = t >> 6, lane = t & 63;
    int nrows = (m1 - m0) * 3;
#pragma unroll 1
    for (int cc = 0; cc < 32; ++cc) {
        int co = w * 32 + cc;
        float* op = Sws + ((size_t)e * NCH + co) * TSTRIDE + dg * DGSTRIDE + m0 * 3;
#pragma unroll
        for (int rr = lane; rr < 84; rr += 64)
            if (rr < nrows) op[rr] = tile[rr * 129 + co];
    }
}

// ---------------- main contraction helper: NB chunks per wave ----------------
template <int NB>
__device__ __forceinline__ void do_chunks(
    const float* __restrict__ tab, const float* __restrict__ nf,
    const int* __restrict__ list, const int* __restrict__ chunkinfo,
    float* __restrict__ prep, int c, int gi, int lane)
{
    int pos[NB];
    float x[NB][9];
#pragma unroll
    for (int u = 0; u < NB; ++u) {
        int info = __builtin_amdgcn_readfirstlane(chunkinfo[gi + u]);
        pos[u] = (info & 0xffff) + lane;
        int b = list[pos[u]];
        const float* xp = nf + ((size_t)(b < 0 ? 0 : b) * 128 + c) * 9;
#pragma unroll
        for (int n = 0; n < 9; ++n) x[u][n] = (b >= 0) ? xp[n] : 0.0f;
    }

#pragma unroll 1
    for (int dg = 0; dg < 3; ++dg) {
        const float* s = tab + dg * DGSTRIDE;   // LDS, wave-uniform addrs
        float a3[NB][3];
#pragma unroll
        for (int u = 0; u < NB; ++u)
#pragma unroll
            for (int d = 0; d < 3; ++d) a3[u][d] = 0.0f;
        int p = 0;
#pragma unroll
        for (int i = 0; i < 9; ++i) {
            float a2[NB][3];
#pragma unroll
            for (int d = 0; d < 3; ++d) {
                float tv = s[p + d];
#pragma unroll
                for (int u = 0; u < NB; ++u) a2[u][d] = tv;
            }
            p += 3;
#pragma unroll
            for (int j = i; j < 9; ++j) {
                float a1[NB][3];
#pragma unroll
                for (int d = 0; d < 3; ++d) {
                    float tv = s[p + d];
#pragma unroll
                    for (int u = 0; u < NB; ++u) a1[u][d] = tv;
                }
                p += 3;
#pragma unroll
                for (int n = j; n < 9; ++n) {
#pragma unroll
                    for (int d = 0; d < 3; ++d) {
                        float tv = s[p + d];
#pragma unroll
                        for (int u = 0; u < NB; ++u)
                            a1[u][d] = fmaf(tv, x[u][n], a1[u][d]);
                    }
                    p += 3;
                }
#pragma unroll
                for (int u = 0; u < NB; ++u)
#pragma unroll
                    for (int d = 0; d < 3; ++d)
                        a2[u][d] = fmaf(a1[u][d], x[u][j], a2[u][d]);
            }
#pragma unroll
            for (int u = 0; u < NB; ++u)
#pragma unroll
                for (int d = 0; d < 3; ++d)
                    a3[u][d] = fmaf(a2[u][d], x[u][i], a3[u][d]);
        }
#pragma unroll
        for (int u = 0; u < NB; ++u)
#pragma unroll
            for (int d = 0; d < 3; ++d)
                prep[(size_t)(dg * 3 + d) * PADN + pos[u]] = a3[u][d];
    }
}

// ---------------- main contraction: block = (c, e), shared 8 KB table, wave = 2 chunks ----------------
__global__ __launch_bounds__(256) void k_main(
    const float* __restrict__ nf, const int* __restrict__ list,
    const int* __restrict__ chunkinfo, const float* __restrict__ Sws,
    float* __restrict__ pre)
{
    __shared__ __align__(16) float tab[TSTRIDE];   // 8 KB, shared by all 4 waves
    int c = blockIdx.x, e = blockIdx.y;
    int t = threadIdx.x;
    int w = t >> 6, lane = t & 63;
    int cb0 = chunkinfo[80 + e], cb1 = chunkinfo[81 + e];
    if (cb0 >= cb1) return;

    {   // stage the (e,c) table once (coalesced, 2 x float4/thread)
        const float4* src = (const float4*)(Sws + ((size_t)e * NCH + c) * TSTRIDE);
        float4* dst = (float4*)tab;
        dst[t] = src[t];
        dst[t + 256] = src[t + 256];
    }
    __syncthreads();

    float* prep = pre + (size_t)c * 9 * PADN;

#pragma unroll 1
    for (int gi = cb0 + 2 * w; gi < cb1; gi += 8) {
        if (gi + 1 < cb1)
            do_chunks<2>(tab, nf, list, chunkinfo, prep, c, gi, lane);
        else
            do_chunks<1>(tab, nf, list, chunkinfo, prep, c, gi, lane);
    }
}

// ---------------- channel-mix GEMM: mixed[f][n] = nrm * sum_c lin[c][f] * pre[c][n] ----------------
__global__ __launch_bounds__(256) void k_mix(
    const float* __restrict__ pre, const int* __restrict__ chunkinfo,
    const float* __restrict__ lin0, const float* __restrict__ lin1,
    const float* __restrict__ lin2, float* __restrict__ mixed)
{
    __shared__ __align__(16) float pt[128 * 64];   // 32 KB
    int bid = blockIdx.x;
    int nt = bid >> 1;                 // n-tile 0..665
    int fbase = (bid & 1) * 64;        // adjacent blocks share the n-tile (L2 reuse)
    int n0 = nt * 64;
    int D = nt / NCHUNK;
    int g = nt - D * NCHUNK;
    if (chunkinfo[g] == -1) return;
    const float* lin = (D == 0) ? lin0 : (D < 4 ? lin1 : lin2);
    int t = threadIdx.x;

    {
        int q4 = (t & 15) * 4;
        int cb = t >> 4;
#pragma unroll
        for (int k = 0; k < 8; ++k) {
            int c = cb + k * 16;
            float4 v = *(const float4*)&pre[(size_t)c * 9 * PADN + n0 + q4];
            *(float4*)&pt[c * 64 + q4] = v;
        }
    }
    __syncthreads();

    int tq = t & 63;
    int f0 = fbase + __builtin_amdgcn_readfirstlane(t >> 6) * 16;
    float acc[16];
#pragma unroll
    for (int f = 0; f < 16; ++f) acc[f] = 0.0f;

#pragma unroll 4
    for (int c = 0; c < 128; ++c) {
        float pv = pt[c * 64 + tq];
        const float* lr = lin + c * 128 + f0;
#pragma unroll
        for (int f = 0; f < 16; ++f)
            acc[f] = fmaf(pv, lr[f], acc[f]);
    }

    const float nrm = 0.08838834764831845f;   // 1/sqrt(128)
#pragma unroll
    for (int f = 0; f < 16; ++f)
        mixed[(size_t)(f0 + f) * 9 * PADN + n0 + tq] = acc[f] * nrm;
}

// ---------------- output permute + sc add ----------------
__global__ __launch_bounds__(256) void k_out(
    const float* __restrict__ mixed, const int* __restrict__ list,
    const int* __restrict__ chunkinfo, const float* __restrict__ sc,
    float* __restrict__ out)
{
    __shared__ float tr[64 * 73];      // [q][row], row = f*9+D, pad 73
    int fc = blockIdx.x, g = blockIdx.y;
    if (chunkinfo[g] == -1) return;
    int t = threadIdx.x;
    int fbase = fc * 8;
    int tf = t >> 6, tq = t & 63;

    // phase 1: load 72 rows x 64 q, coalesced along q
#pragma unroll
    for (int k = 0; k < 18; ++k) {
        int row = k * 4 + tf;                      // 0..71
        int f = row / 9, D = row - f * 9;
        float v = mixed[((size_t)(fbase + f) * 9 + D) * PADN + g * 64 + tq];
        tr[tq * 73 + row] = v;
    }
    __syncthreads();

    // phase 2: 64 nodes * 72 out-cols, contiguous segments per node
#pragma unroll 1
    for (int k = 0; k < 18; ++k) {
        int idx = k * 256 + t;
        int node = idx / 72, col = idx - node * 72;
        int b = list[g * 64 + node];
        if (b < 0) continue;
        int row, gcol;
        if (col < 8)       { row = col * 9;                       gcol = fbase + col; }
        else if (col < 32) { int u = col - 8;  int f = u / 3, dl = u - f * 3;
                             row = f * 9 + 1 + dl;                gcol = 128 + fbase * 3 + u; }
        else               { int u = col - 32; int f = u / 5, dl = u - f * 5;
                             row = f * 9 + 4 + dl;                gcol = 512 + fbase * 5 + u; }
        out[(size_t)b * 1152 + gcol] = tr[node * 73 + row] + sc[(size_t)b * 1152 + gcol];
    }
}

// ---------------- launch ----------------
extern "C" void kernel_launch(void* const* d_in, const int* in_sizes, int n_in,
                              void* d_out, int out_size, void* d_ws, size_t ws_size,
                              hipStream_t stream)
{
    const float* nf    = (const float*)d_in[0];
    const float* sc    = (const float*)d_in[1];
    const float* attrs = (const float*)d_in[2];
    const float *U3s[3], *U2s[3], *U1s[3], *W3s[3], *W2s[3], *W1s[3], *lins[3];
    for (int L = 0; L < 3; ++L) {
        const int o = 3 + 7 * L;
        U3s[L]  = (const float*)d_in[o + 0];
        U2s[L]  = (const float*)d_in[o + 1];
        U1s[L]  = (const float*)d_in[o + 2];
        W3s[L]  = (const float*)d_in[o + 3];
        W2s[L]  = (const float*)d_in[o + 4];
        W1s[L]  = (const float*)d_in[o + 5];
        lins[L] = (const float*)d_in[o + 6];
    }

    float* wsf     = (float*)d_ws;
    int* chunkinfo = (int*)d_ws;
    int* list      = chunkinfo + 96;
    float* Sws   = wsf + 4864;
    float* pre   = Sws + (size_t)NE * NCH * TSTRIDE;     // 2,621,440
    float* mixed = pre + (size_t)NCH * 9 * PADN;         // 5,455,872
    float* wcat  = mixed + (size_t)NCH * 9 * PADN;       // 5,455,872
    float* Usym  = wcat + (size_t)3 * NE * 48 * 128;     // 184,320

    k_prep<<<20, 1024, 0, stream>>>(attrs,
                                    U3s[0], U3s[1], U3s[2], W3s[0], W3s[1], W3s[2],
                                    U2s[0], U2s[1], U2s[2], W2s[0], W2s[1], W2s[2],
                                    U1s[0], U1s[1], U1s[2], W1s[0], W1s[1], W1s[2],
                                    list, chunkinfo, wcat, Usym);
    k_tab<<<240, 256, 0, stream>>>(wcat, Usym, Sws);
    k_main<<<dim3(128, 10), 256, 0, stream>>>(nf, list, chunkinfo, Sws, pre);
    k_mix<<<1332, 256, 0, stream>>>(pre, chunkinfo, lins[0], lins[1], lins[2], mixed);
    k_out<<<dim3(16, NCHUNK), 256, 0, stream>>>(mixed, list, chunkinfo, sc, (float*)d_out);
}